// Round 8
// baseline (83.006 us; speedup 1.0000x reference)
//
#include <hip/hip_runtime.h>
#include <math.h>

#define BB 32
#define PP 8732
#define MM 16
#define NC 81
#define THRESH 0.5f
#define NPR 3
#define CHUNKS 16
#define CHUNK ((PP + CHUNKS - 1) / CHUNKS)   // 546
#define SBLK 64                              // conf blocks per image

// ---------------------------------------------------------------------------
// Kernel A: per-prior match (ovl/obj) + per-object best-prior keys.
// grid = BB*CHUNKS; block (b,c) handles priors [c*CHUNK, ...) of image b.
//   key = (iou_bits << 32) | (0x7FFFFFFF - p)
// iou >= 0 -> float bits monotonic; ties -> larger key = smaller p =
// first-occurrence argmax (jnp.argmax semantics). Every keys_part slot written
// unconditionally -> no zero-init, no atomics, replay-deterministic.
// Block 0 zeroes the completion counter consumed by kernel D.
// ---------------------------------------------------------------------------
__global__ void __launch_bounds__(256) match_part_kernel(
    const float* __restrict__ boxes,   // [B,M,4] xy
    const float* __restrict__ priors,  // [P,4] cxcy
    float* __restrict__ ovl,           // [B,P]
    int* __restrict__ obj,             // [B,P]
    unsigned long long* __restrict__ keys_part,  // [B,CHUNKS,M]
    unsigned* __restrict__ done)       // [1]
{
    const int b = blockIdx.x / CHUNKS;
    const int c = blockIdx.x % CHUNKS;
    const int tid = threadIdx.x;
    if (blockIdx.x == 0 && tid == 0) *done = 0u;

    __shared__ float s_box[MM][4];
    __shared__ float s_area[MM];
    __shared__ float s_bv[4 * MM];
    __shared__ int   s_bi[4 * MM];

    if (tid < MM * 4) ((float*)s_box)[tid] = boxes[b * MM * 4 + tid];
    __syncthreads();
    if (tid < MM)
        s_area[tid] = (s_box[tid][2] - s_box[tid][0]) * (s_box[tid][3] - s_box[tid][1]);
    __syncthreads();

    float bestv[MM];
    int   bestp[MM];
#pragma unroll
    for (int m = 0; m < MM; ++m) { bestv[m] = -1.0f; bestp[m] = 0; }

    const int p0 = c * CHUNK;
    const int p1 = (p0 + CHUNK < PP) ? (p0 + CHUNK) : PP;
    for (int p = p0 + tid; p < p1; p += 256) {
        const float4 pr = ((const float4*)priors)[p];
        float px0 = pr.x - pr.z * 0.5f, py0 = pr.y - pr.w * 0.5f;
        float px1 = pr.x + pr.z * 0.5f, py1 = pr.y + pr.w * 0.5f;
        float parea = (px1 - px0) * (py1 - py0);
        float bv = -1.0f; int bm = 0;
#pragma unroll
        for (int m = 0; m < MM; ++m) {
            float lx = fmaxf(s_box[m][0], px0);
            float ly = fmaxf(s_box[m][1], py0);
            float rx = fminf(s_box[m][2], px1);
            float ry = fminf(s_box[m][3], py1);
            float w = fmaxf(rx - lx, 0.0f);
            float h = fmaxf(ry - ly, 0.0f);
            float inter = w * h;
            float iou = inter / (s_area[m] + parea - inter);
            if (iou > bv) { bv = iou; bm = m; }                   // first occurrence over m
            if (iou > bestv[m]) { bestv[m] = iou; bestp[m] = p; } // p ascending per thread
        }
        ovl[b * PP + p] = bv;
        obj[b * PP + p] = bm;
    }

    const int lane = tid & 63, wid = tid >> 6;
#pragma unroll
    for (int m = 0; m < MM; ++m) {
        float v = bestv[m]; int i = bestp[m];
        for (int off = 32; off > 0; off >>= 1) {
            float ov = __shfl_xor(v, off);
            int   oi = __shfl_xor(i, off);
            if (ov > v || (ov == v && oi < i)) { v = ov; i = oi; }
        }
        if (lane == 0) { s_bv[wid * MM + m] = v; s_bi[wid * MM + m] = i; }
    }
    __syncthreads();

    if (tid == 0) {
        for (int m = 0; m < MM; ++m) {
            float v = s_bv[m]; int i = s_bi[m];
            for (int w = 1; w < 4; ++w) {
                float ov = s_bv[w * MM + m]; int oi = s_bi[w * MM + m];
                if (ov > v || (ov == v && oi < i)) { v = ov; i = oi; }
            }
            if (v < 0.0f) v = 0.0f;  // keep bits nonneg/monotonic
            keys_part[(b * CHUNKS + c) * MM + m] =
                ((unsigned long long)__float_as_uint(v) << 32) |
                (unsigned long long)(0x7FFFFFFFu - (unsigned)i);
        }
    }
}

// ---------------------------------------------------------------------------
// Kernel B: chunk-reduce + force-match scatter. One block of 512 threads:
// thread (b,m) reduces its 16 chunk keys, then 32 threads scatter m-ascending
// (duplicate best-priors resolve last-write-wins = numpy scatter semantics).
// ---------------------------------------------------------------------------
__global__ void __launch_bounds__(512) force_match_kernel(
    const unsigned long long* __restrict__ keys_part,
    float* __restrict__ ovl, int* __restrict__ obj)
{
    __shared__ int s_p[BB * MM];
    const int tid = threadIdx.x;           // 0..511 = b*16+m
    const int b = tid >> 4, m = tid & 15;

    unsigned long long best = 0ull;
#pragma unroll
    for (int c = 0; c < CHUNKS; ++c) {
        unsigned long long k = keys_part[(b * CHUNKS + c) * MM + m];
        if (k > best) best = k;
    }
    s_p[tid] = (int)(0x7FFFFFFFu - (unsigned)(best & 0xFFFFFFFFull));
    __syncthreads();

    if (m == 0) {
        for (int mm = 0; mm < MM; ++mm) {   // m ascending: last write wins
            int p = s_p[(b << 4) + mm];
            obj[b * PP + p] = mm;
            ovl[b * PP + p] = 1.0f;
        }
    }
}

// ---------------------------------------------------------------------------
// Kernel C: conf (R4's exact hot loop — best measured). Block = b*SBLK+s;
// 16 lanes per row; scalar e0..e5 loads (aligned dwords); register
// accumulation -> per-block partials; no global atomics.
// ---------------------------------------------------------------------------
__global__ void __launch_bounds__(256) conf_kernel(
    const float* __restrict__ logits,  // [B,P,81]
    const float* __restrict__ plocs,   // [B,P,4]
    const float* __restrict__ boxes,   // [B,M,4] xy
    const int*   __restrict__ labels,  // [B,M]
    const float* __restrict__ priors,  // [P,4] cxcy
    const float* __restrict__ ovl,     // [B,P]
    const int*   __restrict__ obj,     // [B,P]
    float* __restrict__ neg,           // [B,P]
    int*   __restrict__ cnt_part,      // [BB*SBLK]
    float* __restrict__ conf_part,     // [BB*SBLK]
    float* __restrict__ loc_part)      // [BB*SBLK]
{
    const int tid = threadIdx.x;
    const int lane = tid & 63;
    const int g = lane >> 4;          // row group within wave (0..3)
    const int i = lane & 15;          // lane within group
    const int b = blockIdx.x / SBLK;
    const int s = blockIdx.x % SBLK;
    const int w0 = s * 4 + (tid >> 6);
    const int GPI = PP / 4;           // 2183

    int   pcnt = 0;
    float pconf = 0.0f, ploc = 0.0f;

    for (int wi = w0; wi < GPI; wi += SBLK * 4) {
        const int rp = wi * 4 + g;               // row within image
        const int r = b * PP + rp;               // global row
        const float ov = ovl[r];
        const int o = obj[r];
        const int lab = labels[b * MM + o];

        const size_t base = (size_t)r * NC;
        float e0 = logits[base + i];
        float e1 = logits[base + 16 + i];
        float e2 = logits[base + 32 + i];
        float e3 = logits[base + 48 + i];
        float e4 = logits[base + 64 + i];
        float e5 = (i == 0) ? logits[base + 80] : -INFINITY;

        float mx = fmaxf(fmaxf(fmaxf(e0, e1), fmaxf(e2, e3)), fmaxf(e4, e5));
#pragma unroll
        for (int off = 8; off > 0; off >>= 1) mx = fmaxf(mx, __shfl_xor(mx, off));
        float sum = __expf(e0 - mx) + __expf(e1 - mx) + __expf(e2 - mx) +
                    __expf(e3 - mx) + __expf(e4 - mx) +
                    ((i == 0) ? __expf(e5 - mx) : 0.0f);
#pragma unroll
        for (int off = 8; off > 0; off >>= 1) sum += __shfl_xor(sum, off);

        const int cls = (ov < THRESH) ? 0 : lab;
        const int k = cls >> 4, ci = cls & 15;   // cls==80 -> k=5,ci=0 (lane 0 holds e5)
        float ek = (k == 0) ? e0 : (k == 1) ? e1 : (k == 2) ? e2 :
                   (k == 3) ? e3 : (k == 4) ? e4 : e5;
        float xc = __shfl(ek, (g << 4) + ci);
        float conf = mx + __logf(sum) - xc;
        if (!isfinite(conf)) conf = 0.0f;

        if (i == 0) {
            neg[r] = (cls == 0) ? conf : 0.0f;
            if (cls != 0) {
                pcnt += 1;
                pconf += conf;
                const float4 bx = ((const float4*)boxes)[b * MM + o];
                float cx = (bx.x + bx.z) * 0.5f;
                float cy = (bx.y + bx.w) * 0.5f;
                float w4 = bx.z - bx.x;
                float h4 = bx.w - bx.y;
                const float4 pr = ((const float4*)priors)[rp];
                float g0 = (cx - pr.x) / (pr.z / 10.0f);
                float g1 = (cy - pr.y) / (pr.w / 10.0f);
                float g2 = logf(w4 / pr.z) * 5.0f;
                float g3 = logf(h4 / pr.w) * 5.0f;
                const float4 pl = ((const float4*)plocs)[r];
                ploc += fabsf(pl.x - g0) + fabsf(pl.y - g1) +
                        fabsf(pl.z - g2) + fabsf(pl.w - g3);
            }
        }
    }

    __shared__ int   s4i[4];
    __shared__ float s4c[4], s4l[4];
#pragma unroll
    for (int off = 32; off > 0; off >>= 1) {
        pcnt  += __shfl_xor(pcnt, off);
        pconf += __shfl_xor(pconf, off);
        ploc  += __shfl_xor(ploc, off);
    }
    const int wv = tid >> 6;
    if (lane == 0) { s4i[wv] = pcnt; s4c[wv] = pconf; s4l[wv] = ploc; }
    __syncthreads();
    if (tid == 0) {
        cnt_part[blockIdx.x]  = s4i[0] + s4i[1] + s4i[2] + s4i[3];
        conf_part[blockIdx.x] = s4c[0] + s4c[1] + s4c[2] + s4c[3];
        loc_part[blockIdx.x]  = s4l[0] + s4l[1] + s4l[2] + s4l[3];
    }
}

// ---------------------------------------------------------------------------
// Kernel D: per-image exact top-K sum via 2-bit (3-probe) bisection on the
// nonneg float bit pattern (16 sync-rounds). Values staged in registers.
// Fused final combine via last-block pattern (counter zeroed by kernel A).
// ---------------------------------------------------------------------------
#define TPK 1024
#define VPT ((PP + TPK - 1) / TPK)   // 9

__global__ void __launch_bounds__(TPK) topk_final_kernel(
    const float* __restrict__ neg, const int* __restrict__ cnt_part,
    const float* __restrict__ conf_part, const float* __restrict__ loc_part,
    float* __restrict__ hardneg, unsigned* __restrict__ done,
    float* __restrict__ out)
{
    const int b = blockIdx.x;
    const int tid = threadIdx.x;
    const int lane = tid & 63, wid = tid >> 6;
    __shared__ int s16a[16], s16b[16];
    __shared__ float s16f[16];
    __shared__ int s_k;
    __shared__ int s_last;

    if (tid < 64) {
        int c = cnt_part[b * SBLK + tid];
#pragma unroll
        for (int off = 32; off > 0; off >>= 1) c += __shfl_xor(c, off);
        if (tid == 0) s_k = NPR * c;
    }

    unsigned v[VPT];
#pragma unroll
    for (int j = 0; j < VPT; ++j) {
        int p = tid + j * TPK;
        v[j] = (p < PP) ? __float_as_uint(neg[b * PP + p]) : 0u;
    }
    __syncthreads();

    int K = s_k;
    if (K > PP) K = PP;
    if (K > 0) {   // always true (force-match guarantees >=16 positives)
        unsigned lo = 0u;
        {
            const unsigned m1 = 0x40000000u;
            int c1 = 0;
#pragma unroll
            for (int j = 0; j < VPT; ++j) c1 += (v[j] >= m1);
#pragma unroll
            for (int off = 32; off > 0; off >>= 1) c1 += __shfl_xor(c1, off);
            if (lane == 0) s16a[wid] = c1;
            __syncthreads();
            int n1 = 0;
#pragma unroll
            for (int j = 0; j < 16; ++j) n1 += s16a[j];
            __syncthreads();
            if (n1 >= K) lo = m1;
        }
        unsigned span = 0x40000000u;
        for (int it = 0; it < 15; ++it) {
            span >>= 2;
            const unsigned m1 = lo + span;
            const unsigned m2 = lo + 2 * span;
            const unsigned m3 = lo + 3 * span;
            int c12 = 0, c3 = 0;
#pragma unroll
            for (int j = 0; j < VPT; ++j) {
                c12 += (v[j] >= m1) + ((int)(v[j] >= m2) << 16);
                c3  += (v[j] >= m3);
            }
#pragma unroll
            for (int off = 32; off > 0; off >>= 1) {
                c12 += __shfl_xor(c12, off);
                c3  += __shfl_xor(c3, off);
            }
            if (lane == 0) { s16a[wid] = c12; s16b[wid] = c3; }
            __syncthreads();
            int t12 = 0, t3 = 0;
#pragma unroll
            for (int j = 0; j < 16; ++j) { t12 += s16a[j]; t3 += s16b[j]; }
            __syncthreads();
            const int n1 = t12 & 0xFFFF, n2 = t12 >> 16, n3 = t3;
            lo = (n3 >= K) ? m3 : (n2 >= K) ? m2 : (n1 >= K) ? m1 : lo;
        }
        const unsigned kth = lo;

        int cgt = 0; float sgt = 0.0f;
#pragma unroll
        for (int j = 0; j < VPT; ++j) {
            if (v[j] > kth) { cgt++; sgt += __uint_as_float(v[j]); }
        }
#pragma unroll
        for (int off = 32; off > 0; off >>= 1) {
            cgt += __shfl_xor(cgt, off);
            sgt += __shfl_xor(sgt, off);
        }
        if (lane == 0) { s16a[wid] = cgt; s16f[wid] = sgt; }
        __syncthreads();
        if (tid == 0) {
            int cgt_t = 0; float sum_gt = 0.0f;
#pragma unroll
            for (int j = 0; j < 16; ++j) { cgt_t += s16a[j]; sum_gt += s16f[j]; }
            hardneg[b] = sum_gt + (float)(K - cgt_t) * __uint_as_float(kth);
        }
    } else {
        if (tid == 0) hardneg[b] = 0.0f;
    }

    // -------- last block performs the final combine --------
    __threadfence();
    if (tid == 0) {
        unsigned old = atomicAdd(done, 1u);
        s_last = (old == BB - 1) ? 1 : 0;
    }
    __syncthreads();
    if (!s_last) return;
    __threadfence();

    int np = 0; float cf = 0.0f, lc = 0.0f, hn = 0.0f;
    for (int j = tid; j < BB * SBLK; j += TPK) {
        np += cnt_part[j];
        cf += conf_part[j];
        lc += loc_part[j];
    }
    if (tid < BB) hn = hardneg[tid];
#pragma unroll
    for (int off = 32; off > 0; off >>= 1) {
        np += __shfl_xor(np, off);
        cf += __shfl_xor(cf, off);
        lc += __shfl_xor(lc, off);
        hn += __shfl_xor(hn, off);
    }
    __shared__ float s16l[16], s16h[16];
    if (lane == 0) { s16a[wid] = np; s16f[wid] = cf; s16l[wid] = lc; s16h[wid] = hn; }
    __syncthreads();
    if (tid == 0) {
        int npt_i = 0; float cft = 0.0f, lct = 0.0f, hnt = 0.0f;
#pragma unroll
        for (int j = 0; j < 16; ++j) {
            npt_i += s16a[j]; cft += s16f[j]; lct += s16l[j]; hnt += s16h[j];
        }
        float npt = (float)npt_i;
        out[0] = (hnt + cft) / npt + lct / (4.0f * npt);
    }
}

extern "C" void kernel_launch(void* const* d_in, const int* in_sizes, int n_in,
                              void* d_out, int out_size, void* d_ws, size_t ws_size,
                              hipStream_t stream) {
    (void)in_sizes; (void)n_in; (void)out_size; (void)ws_size;
    const float* plocs  = (const float*)d_in[0];
    const float* logits = (const float*)d_in[1];
    const float* boxes  = (const float*)d_in[2];
    const int*   labels = (const int*)d_in[3];
    const float* priors = (const float*)d_in[4];
    float* out = (float*)d_out;

    char* ws = (char*)d_ws;
    float* ovl      = (float*)ws; ws += (size_t)BB * PP * 4;
    int*   obj      = (int*)ws;   ws += (size_t)BB * PP * 4;
    float* neg      = (float*)ws; ws += (size_t)BB * PP * 4;
    unsigned long long* keys_part = (unsigned long long*)ws; ws += (size_t)BB * CHUNKS * MM * 8;
    int*   cnt_part  = (int*)ws;   ws += BB * SBLK * 4;
    float* conf_part = (float*)ws; ws += BB * SBLK * 4;
    float* loc_part  = (float*)ws; ws += BB * SBLK * 4;
    float* hardneg   = (float*)ws; ws += BB * 4;
    unsigned* done   = (unsigned*)ws; ws += 4;

    // No memset: every ws byte read is unconditionally written earlier in the
    // same call (ovl/obj/keys_part by A, overrides by B, neg/partials by C,
    // done zeroed by A block 0).

    match_part_kernel<<<BB * CHUNKS, 256, 0, stream>>>(boxes, priors, ovl, obj,
                                                       keys_part, done);

    force_match_kernel<<<1, 512, 0, stream>>>(keys_part, ovl, obj);

    conf_kernel<<<BB * SBLK, 256, 0, stream>>>(logits, plocs, boxes, labels, priors,
                                               ovl, obj, neg,
                                               cnt_part, conf_part, loc_part);

    topk_final_kernel<<<BB, TPK, 0, stream>>>(neg, cnt_part, conf_part, loc_part,
                                              hardneg, done, out);
}

// Round 9
// 72.529 us; speedup vs baseline: 1.1445x; 1.1445x over previous
//
#include <hip/hip_runtime.h>
#include <math.h>

#define BB 32
#define PP 8732
#define MM 16
#define NC 81
#define THRESH 0.5f
#define NPR 3
#define CHUNKS 16
#define CHUNK ((PP + CHUNKS - 1) / CHUNKS)   // 546
#define SBLK 64                              // conf blocks per image

// ---------------------------------------------------------------------------
// Kernel A1: partitioned matching (EXACT best-measured R4 config).
// grid = BB*CHUNKS blocks; block (b,c) handles priors [c*CHUNK, ...) of image
// b: writes per-prior best overlap/object and per-chunk best-prior keys.
//   key = (iou_bits << 32) | (0x7FFFFFFF - p)
// iou >= 0 -> float bits monotonic; ties -> larger key = smaller p =
// first-occurrence argmax (jnp.argmax semantics). Every slot written
// unconditionally -> no zero-init, no atomics, replay-deterministic.
// ---------------------------------------------------------------------------
__global__ void __launch_bounds__(256) match_part_kernel(
    const float* __restrict__ boxes,   // [B,M,4] xy
    const float* __restrict__ priors,  // [P,4] cxcy
    float* __restrict__ ovl,           // [B,P]
    int* __restrict__ obj,             // [B,P]
    unsigned long long* __restrict__ keys_part)  // [B,CHUNKS,M]
{
    const int b = blockIdx.x / CHUNKS;
    const int c = blockIdx.x % CHUNKS;
    const int tid = threadIdx.x;
    __shared__ float s_box[MM][4];
    __shared__ float s_area[MM];
    __shared__ float s_bv[4 * MM];
    __shared__ int   s_bi[4 * MM];

    if (tid < MM * 4) ((float*)s_box)[tid] = boxes[b * MM * 4 + tid];
    __syncthreads();
    if (tid < MM)
        s_area[tid] = (s_box[tid][2] - s_box[tid][0]) * (s_box[tid][3] - s_box[tid][1]);
    __syncthreads();

    float bestv[MM];
    int   bestp[MM];
#pragma unroll
    for (int m = 0; m < MM; ++m) { bestv[m] = -1.0f; bestp[m] = 0; }

    const int p0 = c * CHUNK;
    const int p1 = (p0 + CHUNK < PP) ? (p0 + CHUNK) : PP;
    for (int p = p0 + tid; p < p1; p += 256) {
        const float4 pr = ((const float4*)priors)[p];
        float px0 = pr.x - pr.z * 0.5f, py0 = pr.y - pr.w * 0.5f;
        float px1 = pr.x + pr.z * 0.5f, py1 = pr.y + pr.w * 0.5f;
        float parea = (px1 - px0) * (py1 - py0);
        float bv = -1.0f; int bm = 0;
#pragma unroll
        for (int m = 0; m < MM; ++m) {
            float lx = fmaxf(s_box[m][0], px0);
            float ly = fmaxf(s_box[m][1], py0);
            float rx = fminf(s_box[m][2], px1);
            float ry = fminf(s_box[m][3], py1);
            float w = fmaxf(rx - lx, 0.0f);
            float h = fmaxf(ry - ly, 0.0f);
            float inter = w * h;
            float iou = inter / (s_area[m] + parea - inter);
            if (iou > bv) { bv = iou; bm = m; }                   // first occurrence over m
            if (iou > bestv[m]) { bestv[m] = iou; bestp[m] = p; } // p ascending per thread
        }
        ovl[b * PP + p] = bv;
        obj[b * PP + p] = bm;
    }

    const int lane = tid & 63, wid = tid >> 6;
#pragma unroll
    for (int m = 0; m < MM; ++m) {
        float v = bestv[m]; int i = bestp[m];
        for (int off = 32; off > 0; off >>= 1) {
            float ov = __shfl_xor(v, off);
            int   oi = __shfl_xor(i, off);
            if (ov > v || (ov == v && oi < i)) { v = ov; i = oi; }
        }
        if (lane == 0) { s_bv[wid * MM + m] = v; s_bi[wid * MM + m] = i; }
    }
    __syncthreads();

    if (tid == 0) {
        for (int m = 0; m < MM; ++m) {
            float v = s_bv[m]; int i = s_bi[m];
            for (int w = 1; w < 4; ++w) {
                float ov = s_bv[w * MM + m]; int oi = s_bi[w * MM + m];
                if (ov > v || (ov == v && oi < i)) { v = ov; i = oi; }
            }
            if (v < 0.0f) v = 0.0f;  // keep bits nonneg/monotonic
            keys_part[(b * CHUNKS + c) * MM + m] =
                ((unsigned long long)__float_as_uint(v) << 32) |
                (unsigned long long)(0x7FFFFFFFu - (unsigned)i);
        }
    }
}

// ---------------------------------------------------------------------------
// Kernel A2: chunk-reduce + force-match scatter. One block of 512 threads:
// thread (b,m) reduces its 16 chunk keys, then 32 threads scatter m-ascending
// (duplicate best-priors resolve last-write-wins = numpy scatter semantics).
// ---------------------------------------------------------------------------
__global__ void __launch_bounds__(512) force_match_kernel(
    const unsigned long long* __restrict__ keys_part,
    float* __restrict__ ovl, int* __restrict__ obj)
{
    __shared__ int s_p[BB * MM];
    const int tid = threadIdx.x;           // 0..511 = b*16+m
    const int b = tid >> 4, m = tid & 15;

    unsigned long long best = 0ull;
#pragma unroll
    for (int c = 0; c < CHUNKS; ++c) {
        unsigned long long k = keys_part[(b * CHUNKS + c) * MM + m];
        if (k > best) best = k;
    }
    s_p[tid] = (int)(0x7FFFFFFFu - (unsigned)(best & 0xFFFFFFFFull));
    __syncthreads();

    if (m == 0) {
        for (int mm = 0; mm < MM; ++mm) {   // m ascending: last write wins
            int p = s_p[(b << 4) + mm];
            obj[b * PP + p] = mm;
            ovl[b * PP + p] = 1.0f;
        }
    }
}

// ---------------------------------------------------------------------------
// Kernel B: conf (EXACT best-measured R4 hot loop). Block = b*SBLK+s; 16 lanes
// per row; scalar e0..e5 loads; register accumulation -> per-block partials.
// ---------------------------------------------------------------------------
__global__ void __launch_bounds__(256) conf_kernel(
    const float* __restrict__ logits,  // [B,P,81]
    const float* __restrict__ plocs,   // [B,P,4]
    const float* __restrict__ boxes,   // [B,M,4] xy
    const int*   __restrict__ labels,  // [B,M]
    const float* __restrict__ priors,  // [P,4] cxcy
    const float* __restrict__ ovl,     // [B,P]
    const int*   __restrict__ obj,     // [B,P]
    float* __restrict__ neg,           // [B,P]
    int*   __restrict__ cnt_part,      // [BB*SBLK]
    float* __restrict__ conf_part,     // [BB*SBLK]
    float* __restrict__ loc_part)      // [BB*SBLK]
{
    const int tid = threadIdx.x;
    const int lane = tid & 63;
    const int g = lane >> 4;          // row group within wave (0..3)
    const int i = lane & 15;          // lane within group
    const int b = blockIdx.x / SBLK;
    const int s = blockIdx.x % SBLK;
    const int w0 = s * 4 + (tid >> 6);
    const int GPI = PP / 4;           // 2183

    int   pcnt = 0;
    float pconf = 0.0f, ploc = 0.0f;

    for (int wi = w0; wi < GPI; wi += SBLK * 4) {
        const int rp = wi * 4 + g;               // row within image
        const int r = b * PP + rp;               // global row
        const float ov = ovl[r];
        const int o = obj[r];
        const int lab = labels[b * MM + o];

        const size_t base = (size_t)r * NC;
        float e0 = logits[base + i];
        float e1 = logits[base + 16 + i];
        float e2 = logits[base + 32 + i];
        float e3 = logits[base + 48 + i];
        float e4 = logits[base + 64 + i];
        float e5 = (i == 0) ? logits[base + 80] : -INFINITY;

        float mx = fmaxf(fmaxf(fmaxf(e0, e1), fmaxf(e2, e3)), fmaxf(e4, e5));
#pragma unroll
        for (int off = 8; off > 0; off >>= 1) mx = fmaxf(mx, __shfl_xor(mx, off));
        float sum = __expf(e0 - mx) + __expf(e1 - mx) + __expf(e2 - mx) +
                    __expf(e3 - mx) + __expf(e4 - mx) +
                    ((i == 0) ? __expf(e5 - mx) : 0.0f);
#pragma unroll
        for (int off = 8; off > 0; off >>= 1) sum += __shfl_xor(sum, off);

        const int cls = (ov < THRESH) ? 0 : lab;
        const int k = cls >> 4, ci = cls & 15;   // cls==80 -> k=5,ci=0 (lane 0 holds e5)
        float ek = (k == 0) ? e0 : (k == 1) ? e1 : (k == 2) ? e2 :
                   (k == 3) ? e3 : (k == 4) ? e4 : e5;
        float xc = __shfl(ek, (g << 4) + ci);
        float conf = mx + __logf(sum) - xc;
        if (!isfinite(conf)) conf = 0.0f;

        if (i == 0) {
            neg[r] = (cls == 0) ? conf : 0.0f;
            if (cls != 0) {
                pcnt += 1;
                pconf += conf;
                const float4 bx = ((const float4*)boxes)[b * MM + o];
                float cx = (bx.x + bx.z) * 0.5f;
                float cy = (bx.y + bx.w) * 0.5f;
                float w4 = bx.z - bx.x;
                float h4 = bx.w - bx.y;
                const float4 pr = ((const float4*)priors)[rp];
                float g0 = (cx - pr.x) / (pr.z / 10.0f);
                float g1 = (cy - pr.y) / (pr.w / 10.0f);
                float g2 = logf(w4 / pr.z) * 5.0f;
                float g3 = logf(h4 / pr.w) * 5.0f;
                const float4 pl = ((const float4*)plocs)[r];
                ploc += fabsf(pl.x - g0) + fabsf(pl.y - g1) +
                        fabsf(pl.z - g2) + fabsf(pl.w - g3);
            }
        }
    }

    __shared__ int   s4i[4];
    __shared__ float s4c[4], s4l[4];
#pragma unroll
    for (int off = 32; off > 0; off >>= 1) {
        pcnt  += __shfl_xor(pcnt, off);
        pconf += __shfl_xor(pconf, off);
        ploc  += __shfl_xor(ploc, off);
    }
    const int wv = tid >> 6;
    if (lane == 0) { s4i[wv] = pcnt; s4c[wv] = pconf; s4l[wv] = ploc; }
    __syncthreads();
    if (tid == 0) {
        cnt_part[blockIdx.x]  = s4i[0] + s4i[1] + s4i[2] + s4i[3];
        conf_part[blockIdx.x] = s4c[0] + s4c[1] + s4c[2] + s4c[3];
        loc_part[blockIdx.x]  = s4l[0] + s4l[1] + s4l[2] + s4l[3];
    }
}

// ---------------------------------------------------------------------------
// Kernel C: per-image exact top-K sum. ONLY change vs best-measured config:
// 1+15x2-bit bisection (16 sync-rounds) instead of 31x1-bit. Values staged in
// registers; separate kernel, no fence/atomic.
// ---------------------------------------------------------------------------
#define TPK 1024
#define VPT ((PP + TPK - 1) / TPK)   // 9

__global__ void __launch_bounds__(TPK) topk_kernel(
    const float* __restrict__ neg, const int* __restrict__ cnt_part,
    float* __restrict__ hardneg)
{
    const int b = blockIdx.x;
    const int tid = threadIdx.x;
    const int lane = tid & 63, wid = tid >> 6;
    __shared__ int s16a[16], s16b[16];
    __shared__ float s16f[16];
    __shared__ int s_k;

    if (tid < 64) {
        int c = cnt_part[b * SBLK + tid];
#pragma unroll
        for (int off = 32; off > 0; off >>= 1) c += __shfl_xor(c, off);
        if (tid == 0) s_k = NPR * c;
    }

    unsigned v[VPT];
#pragma unroll
    for (int j = 0; j < VPT; ++j) {
        int p = tid + j * TPK;
        v[j] = (p < PP) ? __float_as_uint(neg[b * PP + p]) : 0u;
    }
    __syncthreads();

    int K = s_k;
    if (K > PP) K = PP;
    if (K <= 0) { if (tid == 0) hardneg[b] = 0.0f; return; }

    unsigned lo = 0u;
    {
        const unsigned m1 = 0x40000000u;
        int c1 = 0;
#pragma unroll
        for (int j = 0; j < VPT; ++j) c1 += (v[j] >= m1);
#pragma unroll
        for (int off = 32; off > 0; off >>= 1) c1 += __shfl_xor(c1, off);
        if (lane == 0) s16a[wid] = c1;
        __syncthreads();
        int n1 = 0;
#pragma unroll
        for (int j = 0; j < 16; ++j) n1 += s16a[j];
        __syncthreads();
        if (n1 >= K) lo = m1;
    }
    unsigned span = 0x40000000u;
    for (int it = 0; it < 15; ++it) {
        span >>= 2;
        const unsigned m1 = lo + span;
        const unsigned m2 = lo + 2 * span;
        const unsigned m3 = lo + 3 * span;
        int c12 = 0, c3 = 0;
#pragma unroll
        for (int j = 0; j < VPT; ++j) {
            c12 += (v[j] >= m1) + ((int)(v[j] >= m2) << 16);
            c3  += (v[j] >= m3);
        }
#pragma unroll
        for (int off = 32; off > 0; off >>= 1) {
            c12 += __shfl_xor(c12, off);
            c3  += __shfl_xor(c3, off);
        }
        if (lane == 0) { s16a[wid] = c12; s16b[wid] = c3; }
        __syncthreads();
        int t12 = 0, t3 = 0;
#pragma unroll
        for (int j = 0; j < 16; ++j) { t12 += s16a[j]; t3 += s16b[j]; }
        __syncthreads();
        const int n1 = t12 & 0xFFFF, n2 = t12 >> 16, n3 = t3;
        lo = (n3 >= K) ? m3 : (n2 >= K) ? m2 : (n1 >= K) ? m1 : lo;
    }
    const unsigned kth = lo;

    int cgt = 0; float sgt = 0.0f;
#pragma unroll
    for (int j = 0; j < VPT; ++j) {
        if (v[j] > kth) { cgt++; sgt += __uint_as_float(v[j]); }
    }
#pragma unroll
    for (int off = 32; off > 0; off >>= 1) {
        cgt += __shfl_xor(cgt, off);
        sgt += __shfl_xor(sgt, off);
    }
    if (lane == 0) { s16a[wid] = cgt; s16f[wid] = sgt; }
    __syncthreads();
    if (tid == 0) {
        int cgt_t = 0; float sum_gt = 0.0f;
#pragma unroll
        for (int j = 0; j < 16; ++j) { cgt_t += s16a[j]; sum_gt += s16f[j]; }
        hardneg[b] = sum_gt + (float)(K - cgt_t) * __uint_as_float(kth);
    }
}

// ---------------------------------------------------------------------------
// Kernel D: final scalar combine; reduces the 2048 per-block partials + 32
// per-image hard-negative sums.
// ---------------------------------------------------------------------------
__global__ void __launch_bounds__(256) final_kernel(
    const int* __restrict__ cnt_part,
    const float* __restrict__ conf_part,
    const float* __restrict__ loc_part,
    const float* __restrict__ hardneg,
    float* __restrict__ out)
{
    const int tid = threadIdx.x;
    const int lane = tid & 63, wid = tid >> 6;
    __shared__ int s4i[4];
    __shared__ float s4c[4], s4l[4], s4h[4];

    int np = 0; float cf = 0.0f, lc = 0.0f, hn = 0.0f;
    for (int j = tid; j < BB * SBLK; j += 256) {
        np += cnt_part[j];
        cf += conf_part[j];
        lc += loc_part[j];
    }
    if (tid < BB) hn = hardneg[tid];

#pragma unroll
    for (int off = 32; off > 0; off >>= 1) {
        np += __shfl_xor(np, off);
        cf += __shfl_xor(cf, off);
        lc += __shfl_xor(lc, off);
        hn += __shfl_xor(hn, off);
    }
    if (lane == 0) { s4i[wid] = np; s4c[wid] = cf; s4l[wid] = lc; s4h[wid] = hn; }
    __syncthreads();
    if (tid == 0) {
        float npt = (float)(s4i[0] + s4i[1] + s4i[2] + s4i[3]);
        float cft = s4c[0] + s4c[1] + s4c[2] + s4c[3];
        float lct = s4l[0] + s4l[1] + s4l[2] + s4l[3];
        float hnt = s4h[0] + s4h[1] + s4h[2] + s4h[3];
        out[0] = (hnt + cft) / npt + lct / (4.0f * npt);
    }
}

extern "C" void kernel_launch(void* const* d_in, const int* in_sizes, int n_in,
                              void* d_out, int out_size, void* d_ws, size_t ws_size,
                              hipStream_t stream) {
    (void)in_sizes; (void)n_in; (void)out_size; (void)ws_size;
    const float* plocs  = (const float*)d_in[0];
    const float* logits = (const float*)d_in[1];
    const float* boxes  = (const float*)d_in[2];
    const int*   labels = (const int*)d_in[3];
    const float* priors = (const float*)d_in[4];
    float* out = (float*)d_out;

    char* ws = (char*)d_ws;
    float* ovl      = (float*)ws; ws += (size_t)BB * PP * 4;
    int*   obj      = (int*)ws;   ws += (size_t)BB * PP * 4;
    float* neg      = (float*)ws; ws += (size_t)BB * PP * 4;
    unsigned long long* keys_part = (unsigned long long*)ws; ws += (size_t)BB * CHUNKS * MM * 8;
    int*   cnt_part  = (int*)ws;   ws += BB * SBLK * 4;
    float* conf_part = (float*)ws; ws += BB * SBLK * 4;
    float* loc_part  = (float*)ws; ws += BB * SBLK * 4;
    float* hardneg   = (float*)ws; ws += BB * 4;

    // No memset: every ws byte read is unconditionally written earlier in the
    // same call (keys_part fully written by A1, ovl/obj by A1+A2, neg/partials
    // by B, hardneg by C).

    match_part_kernel<<<BB * CHUNKS, 256, 0, stream>>>(boxes, priors, ovl, obj, keys_part);
    force_match_kernel<<<1, 512, 0, stream>>>(keys_part, ovl, obj);

    conf_kernel<<<BB * SBLK, 256, 0, stream>>>(logits, plocs, boxes, labels, priors,
                                               ovl, obj, neg,
                                               cnt_part, conf_part, loc_part);

    topk_kernel<<<BB, TPK, 0, stream>>>(neg, cnt_part, hardneg);

    final_kernel<<<1, 256, 0, stream>>>(cnt_part, conf_part, loc_part, hardneg, out);
}